// Round 16
// baseline (137.001 us; speedup 1.0000x reference)
//
#include <hip/hip_runtime.h>

typedef unsigned short u16;
typedef unsigned int u32;
typedef __bf16 bf16x8_t __attribute__((ext_vector_type(8)));
typedef float f32x4_t __attribute__((ext_vector_type(4)));
typedef float f32x16_t __attribute__((ext_vector_type(16)));

#define T_SEQ 4096
#define EMB 512
#define NH 8
#define NKV 2
#define HD 64

__device__ __forceinline__ float bf2f(u16 h) {
    union { unsigned u; float f; } x; x.u = ((unsigned)h) << 16; return x.f;
}
__device__ __forceinline__ u16 f2bf(float f) {
    union { float f; unsigned u; } x; x.f = f;
    unsigned r = x.u + 0x7FFFu + ((x.u >> 16) & 1u);
    return (u16)(r >> 16);
}

// ------------- fused prep: weight transposes + RoPE tables, ONE launch -------------
// flat thread index i over segments (total 786,432 = 3072 blocks x 256):
//   [0, 262144)         WqT
//   [262144, 327680)    WkT
//   [327680, 393216)    WvT
//   [393216, 655360)    WoT
//   [655360, 786432)    rope tables
__global__ __launch_bounds__(256)
void prep_kernel(const float* __restrict__ Wq, const float* __restrict__ Wk,
                 const float* __restrict__ Wv, const float* __restrict__ Wo,
                 u16* __restrict__ WqkvT, u16* __restrict__ WoT,
                 float* __restrict__ cost, float* __restrict__ sint)
{
    int i = blockIdx.x * 256 + threadIdx.x;
    if (i < 262144) {
        int n = i >> 9, k = i & 511;
        WqkvT[i] = f2bf(Wq[(size_t)k * 512 + n]);
    } else if (i < 327680) {
        int j = i - 262144;
        int n = j >> 9, k = j & 511;
        WqkvT[i] = f2bf(Wk[(size_t)k * 128 + n]);
    } else if (i < 393216) {
        int j = i - 327680;
        int n = j >> 9, k = j & 511;
        WqkvT[i] = f2bf(Wv[(size_t)k * 128 + n]);
    } else if (i < 655360) {
        int j = i - 393216;
        int n = j >> 9, k = j & 511;
        WoT[j] = f2bf(Wo[(size_t)k * 512 + n]);
    } else {
        int j = i - 655360;
        int t = j >> 5, jj = j & 31;
        double invf = pow(1.0e6, -(double)jj / 32.0);
        double ang = (double)t * invf;
        cost[j] = (float)cos(ang);
        sint[j] = (float)sin(ang);
    }
}

// ---------------- GEMM: C[M,N] = A[M,K](bf16) @ Bt[N,K](bf16)^T ----------------
// ASRC: 0 = A is bf16 (direct); 1 = A is fp32 (convert in staging);
//       2 = A is split-KV partials: combine (po0+po1)/(l0+l1) in staging (K=512, k0>>6 = h).
// EPI:  0 = fp32 store to C; 1 = QKV epilogue (bias+RoPE+scatter q/k + transposed V).
template <int EPI, int ASRC>
__global__ __launch_bounds__(256)
void gemm_kernel(const u16* __restrict__ A, const float* __restrict__ Af32,
                 const u16* __restrict__ po1, const float* __restrict__ lbp,
                 const u16* __restrict__ Bt, int K,
                 float* __restrict__ C, int N,
                 const float* __restrict__ bq, const float* __restrict__ bk,
                 const float* __restrict__ bv,
                 const float* __restrict__ cost, const float* __restrict__ sint,
                 u16* __restrict__ qw, u16* __restrict__ kw, u16* __restrict__ vt)
{
    __shared__ __align__(16) u16 As[128][72];
    __shared__ __align__(16) u16 Bs[128][72];

    const int tid  = threadIdx.x;
    const int lane = tid & 63, wave = tid >> 6;
    const int wr = wave >> 1, wc = wave & 1;
    const int tm = blockIdx.x, tn = blockIdx.y;
    const int lrow = lane & 15, lgrp = lane >> 4;

    f32x4_t acc[4][4];
#pragma unroll
    for (int i = 0; i < 4; ++i)
#pragma unroll
        for (int j = 0; j < 4; ++j) acc[i][j] = (f32x4_t){0.f, 0.f, 0.f, 0.f};

    for (int k0 = 0; k0 < K; k0 += 64) {
        __syncthreads();
        {
            const int r0 = tid >> 3;
            const int ko = (tid & 7) * 8;
#pragma unroll
            for (int rr = 0; rr < 4; ++rr) {
                int row = r0 + rr * 32;
                int grow = tm * 128 + row;
                if (ASRC == 0) {
                    uint4 va = *reinterpret_cast<const uint4*>(A + (size_t)grow * K + k0 + ko);
                    *reinterpret_cast<uint4*>(&As[row][ko]) = va;
                } else if (ASRC == 1) {
                    float4 f0 = *reinterpret_cast<const float4*>(Af32 + (size_t)grow * K + k0 + ko);
                    float4 f1 = *reinterpret_cast<const float4*>(Af32 + (size_t)grow * K + k0 + ko + 4);
                    u16 o[8] = { f2bf(f0.x), f2bf(f0.y), f2bf(f0.z), f2bf(f0.w),
                                 f2bf(f1.x), f2bf(f1.y), f2bf(f1.z), f2bf(f1.w) };
                    *reinterpret_cast<uint4*>(&As[row][ko]) = *reinterpret_cast<uint4*>(o);
                } else {
                    // fused split-KV combine: grow -> (b,t), k0 -> h, ko = d0
                    int b2 = grow >> 12, t2 = grow & 4095;
                    int h2 = k0 >> 6;
                    size_t prow = (size_t)(b2 * 8 + h2) * 4096 + t2;
                    float inv = 1.0f / (lbp[prow] + lbp[65536 + prow]);
                    uint4 a = *reinterpret_cast<const uint4*>(A   + prow * 64 + ko);
                    uint4 c = *reinterpret_cast<const uint4*>(po1 + prow * 64 + ko);
                    const u16* pa = reinterpret_cast<const u16*>(&a);
                    const u16* pc = reinterpret_cast<const u16*>(&c);
                    u16 o[8];
#pragma unroll
                    for (int j = 0; j < 8; ++j)
                        o[j] = f2bf((bf2f(pa[j]) + bf2f(pc[j])) * inv);
                    *reinterpret_cast<uint4*>(&As[row][ko]) = *reinterpret_cast<uint4*>(o);
                }
                uint4 vb = *reinterpret_cast<const uint4*>(Bt + (size_t)(tn * 128 + row) * K + k0 + ko);
                *reinterpret_cast<uint4*>(&Bs[row][ko]) = vb;
            }
        }
        __syncthreads();
#pragma unroll
        for (int kc = 0; kc < 2; ++kc) {
            bf16x8_t af[4], bf[4];
#pragma unroll
            for (int mb = 0; mb < 4; ++mb)
                af[mb] = *reinterpret_cast<const bf16x8_t*>(&As[wr * 64 + mb * 16 + lrow][kc * 32 + lgrp * 8]);
#pragma unroll
            for (int nb = 0; nb < 4; ++nb)
                bf[nb] = *reinterpret_cast<const bf16x8_t*>(&Bs[wc * 64 + nb * 16 + lrow][kc * 32 + lgrp * 8]);
#pragma unroll
            for (int mb = 0; mb < 4; ++mb)
#pragma unroll
                for (int nb = 0; nb < 4; ++nb)
                    acc[mb][nb] = __builtin_amdgcn_mfma_f32_16x16x32_bf16(af[mb], bf[nb], acc[mb][nb], 0, 0, 0);
        }
    }

    if (EPI == 0) {
#pragma unroll
        for (int mb = 0; mb < 4; ++mb)
#pragma unroll
            for (int nb = 0; nb < 4; ++nb)
#pragma unroll
                for (int r = 0; r < 4; ++r) {
                    int row = tm * 128 + wr * 64 + mb * 16 + lgrp * 4 + r;
                    int col = tn * 128 + wc * 64 + nb * 16 + lrow;
                    C[(size_t)row * N + col] = acc[mb][nb][r];
                }
    } else {
        const float QSC = 0.125f * 1.44269504088896f;   // head_dim^-0.5 * log2(e)
#pragma unroll
        for (int mb = 0; mb < 4; ++mb)
#pragma unroll
            for (int r = 0; r < 4; ++r) {
                int grow = tm * 128 + wr * 64 + mb * 16 + lgrp * 4 + r;
                int b = grow >> 12, t = grow & 4095;
#pragma unroll
                for (int nb = 0; nb < 2; ++nb) {
                    int n = tn * 128 + wc * 64 + nb * 16 + lrow;
                    int j = n & 63;
                    float c0 = acc[mb][nb][r];
                    float c1 = acc[mb][nb + 2][r];
                    if (n < 512) {               // Q (softmax runs in exp2 domain)
                        c0 += bq[n]; c1 += bq[n + 32];
                        float cs = cost[t * 32 + j], sn = sint[t * 32 + j];
                        float r0 = (c0 * cs - c1 * sn) * QSC;
                        float r1 = (c1 * cs + c0 * sn) * QSC;
                        int h = n >> 6;
                        size_t base = ((size_t)(b * NH + h) * T_SEQ + t) * HD;
                        qw[base + j]      = f2bf(r0);
                        qw[base + j + 32] = f2bf(r1);
                    } else if (n < 640) {        // K
                        int nn = n - 512;
                        c0 += bk[nn]; c1 += bk[nn + 32];
                        float cs = cost[t * 32 + j], sn = sint[t * 32 + j];
                        float r0 = c0 * cs - c1 * sn;
                        float r1 = c1 * cs + c0 * sn;
                        int hk2 = nn >> 6;
                        size_t base = ((size_t)(b * NKV + hk2) * T_SEQ + t) * HD;
                        kw[base + j]      = f2bf(r0);
                        kw[base + j + 32] = f2bf(r1);
                    } else {                     // V -> transposed vt[b][hk][d][t]
                        int nn = n - 640;
                        c0 += bv[nn]; c1 += bv[nn + 32];
                        int hv = nn >> 6;
                        size_t base = (size_t)(b * NKV + hv) * HD * T_SEQ;
                        vt[base + (size_t)j * T_SEQ + t]        = f2bf(c0);
                        vt[base + (size_t)(j + 32) * T_SEQ + t] = f2bf(c1);
                    }
                }
            }
    }
}

// ---------------- causal flash attention: split-KV (2 equal chunks), fixed-max softmax ----------------
// r12 config (best measured: 87us): grid (16 bh, 32 qt, 2 ck), x=bh fastest -> XCD-local K/V.
// qt = 31-y heavy-first; chunk ck covers [ck*(qt+1), (ck+1)*(qt+1)). 1024 blocks x 4 waves.
// permlane32_swap P-repack; hoisted-zero QK accumulator; fixed m=16 exp2-domain softmax.
__global__ __launch_bounds__(256)
void attn_kernel(const u16* __restrict__ qw, const u16* __restrict__ kw,
                 const u16* __restrict__ vt, u16* __restrict__ po, float* __restrict__ lb)
{
    __shared__ __align__(16) u16 Ks[2][64][64];   // [buf][kv][d], 16B-granule XOR swizzle
    __shared__ __align__(16) u16 Vs[2][64][64];   // [buf][d][kv], same swizzle

    const int hdix = blockIdx.x;                  // bh (fastest -> XCD L2 locality)
    const int b = hdix >> 3, h = hdix & 7, hk = h >> 2;
    const int qt = 31 - (int)blockIdx.y;          // heavy-first
    const int ck = blockIdx.z;                    // kv chunk
    const int tid = threadIdx.x, lane = tid & 63, wave = tid >> 6;
    const int lid = lane & 31, hi = lane >> 5;
    const int q0 = qt * 128 + wave * 32;
    const int kt0 = ck * (qt + 1);
    const int kt1 = kt0 + (qt + 1);

    const u16* kbase  = kw + (size_t)(b * NKV + hk) * T_SEQ * HD;
    const u16* vtbase = vt + (size_t)(b * NKV + hk) * HD * T_SEQ;

    const int ss = tid >> 3;                 // 0..31
    const int sg = tid & 7;                  // 16B granule
    const int swz = (sg ^ (ss & 7)) << 3;    // (ss+32)&7 == ss&7

    bf16x8_t qf[4];
    {
        const u16* qrow = qw + ((size_t)(b * NH + h) * T_SEQ + q0 + lid) * HD + 8 * hi;
#pragma unroll
        for (int t = 0; t < 4; ++t)
            qf[t] = *reinterpret_cast<const bf16x8_t*>(qrow + 16 * t);
    }

    f32x16_t o0, o1, z16;
#pragma unroll
    for (int i = 0; i < 16; ++i) { o0[i] = 0.f; o1[i] = 0.f; z16[i] = 0.f; }
    const float M_FIX = 16.0f;               // fixed softmax max (exp2 domain)
    float l = 0.f;

    // prologue: stage tile kt0 into buffer 0
    {
        const int s2 = kt0 * 64;
        uint4 ka  = *reinterpret_cast<const uint4*>(kbase + (size_t)(s2 + ss) * HD + sg * 8);
        uint4 kb2 = *reinterpret_cast<const uint4*>(kbase + (size_t)(s2 + ss + 32) * HD + sg * 8);
        uint4 va  = *reinterpret_cast<const uint4*>(vtbase + (size_t)ss * T_SEQ + s2 + sg * 8);
        uint4 vb2 = *reinterpret_cast<const uint4*>(vtbase + (size_t)(ss + 32) * T_SEQ + s2 + sg * 8);
        *reinterpret_cast<uint4*>(&Ks[0][ss][swz]) = ka;
        *reinterpret_cast<uint4*>(&Ks[0][ss + 32][swz]) = kb2;
        *reinterpret_cast<uint4*>(&Vs[0][ss][swz]) = va;
        *reinterpret_cast<uint4*>(&Vs[0][ss + 32][swz]) = vb2;
    }
    __syncthreads();

    for (int kt = kt0; kt < kt1; ++kt) {
        const int cur = (kt - kt0) & 1, nxt = cur ^ 1;
        const bool pre = (kt + 1 < kt1);

        uint4 kr0, kr1, vr0, vr1;
        if (pre) {
            const int s2 = (kt + 1) * 64;
            kr0 = *reinterpret_cast<const uint4*>(kbase + (size_t)(s2 + ss) * HD + sg * 8);
            kr1 = *reinterpret_cast<const uint4*>(kbase + (size_t)(s2 + ss + 32) * HD + sg * 8);
            vr0 = *reinterpret_cast<const uint4*>(vtbase + (size_t)ss * T_SEQ + s2 + sg * 8);
            vr1 = *reinterpret_cast<const uint4*>(vtbase + (size_t)(ss + 32) * T_SEQ + s2 + sg * 8);
        }

        if (kt * 64 <= q0 + 31) {            // wave has visible kv in this tile
            const bool full = (kt * 64 + 32 <= q0 + 31);   // s1 half (kv+32) visible?
            const bool mreq = (kt * 64 + 63 > q0);         // any masking needed?

            // ---- S^T = K_tile . Q^T  (t=0 uses hoisted zero C) ----
            f32x16_t s0, s1;
            __builtin_amdgcn_s_setprio(1);
#pragma unroll
            for (int t = 0; t < 4; ++t) {
                const int g = ((2 * t + hi) ^ (lid & 7)) << 3;
                bf16x8_t ka = *reinterpret_cast<const bf16x8_t*>(&Ks[cur][lid][g]);
                s0 = __builtin_amdgcn_mfma_f32_32x32x16_bf16(ka, qf[t], (t == 0) ? z16 : s0, 0, 0, 0);
                if (full) {
                    bf16x8_t kb2 = *reinterpret_cast<const bf16x8_t*>(&Ks[cur][lid + 32][g]);
                    s1 = __builtin_amdgcn_mfma_f32_32x32x16_bf16(kb2, qf[t], (t == 0) ? z16 : s1, 0, 0, 0);
                }
            }
            __builtin_amdgcn_s_setprio(0);

            // ---- causal mask ----
            if (mreq) {
                const int qg = q0 + lid;
                const int kvb = kt * 64 + 4 * hi;
#pragma unroll
                for (int r = 0; r < 16; ++r) {
                    int kv = kvb + (r & 3) + 8 * (r >> 2);
                    if (kv > qg) s0[r] = -1e30f;
                    if (full && kv + 32 > qg) s1[r] = -1e30f;
                }
            }

            // ---- softmax, exp2 domain, FIXED max ----
#pragma unroll
            for (int r = 0; r < 16; ++r) s0[r] = exp2f(s0[r] - M_FIX);
            if (full) {
#pragma unroll
                for (int r = 0; r < 16; ++r) s1[r] = exp2f(s1[r] - M_FIX);
            }

            {
                float rs = 0.f;
#pragma unroll
                for (int q4 = 0; q4 < 4; ++q4)
                    rs += (s0[4 * q4] + s0[4 * q4 + 1]) + (s0[4 * q4 + 2] + s0[4 * q4 + 3]);
                if (full) {
#pragma unroll
                    for (int q4 = 0; q4 < 4; ++q4)
                        rs += (s1[4 * q4] + s1[4 * q4 + 1]) + (s1[4 * q4 + 2] + s1[4 * q4 + 3]);
                }
                rs += __shfl_xor(rs, 32);
                l += rs;
            }

            // ---- in-register P repack -> PV A-fragments (cvt_pk + permlane32_swap) ----
            bf16x8_t pa[4];
            {
                u32 pw[8];
#pragma unroll
                for (int c = 0; c < 4; ++c) {
                    asm("v_cvt_pk_bf16_f32 %0, %1, %2" : "=v"(pw[2 * c])     : "v"(s0[4 * c]),     "v"(s0[4 * c + 1]));
                    asm("v_cvt_pk_bf16_f32 %0, %1, %2" : "=v"(pw[2 * c + 1]) : "v"(s0[4 * c + 2]), "v"(s0[4 * c + 3]));
                }
                asm("v_permlane32_swap_b32 %0, %1" : "+v"(pw[0]), "+v"(pw[2]));
                asm("v_permlane32_swap_b32 %0, %1" : "+v"(pw[1]), "+v"(pw[3]));
                asm("v_permlane32_swap_b32 %0, %1" : "+v"(pw[4]), "+v"(pw[6]));
                asm("v_permlane32_swap_b32 %0, %1" : "+v"(pw[5]), "+v"(pw[7]));
                uint4 f0 = {pw[0], pw[1], pw[2], pw[3]};
                uint4 f1 = {pw[4], pw[5], pw[6], pw[7]};
                pa[0] = __builtin_bit_cast(bf16x8_t, f0);
                pa[1] = __builtin_bit_cast(bf16x8_t, f1);
                if (full) {
#pragma unroll
                    for (int c = 0; c < 4; ++c) {
                        asm("v_cvt_pk_bf16_f32 %0, %1, %2" : "=v"(pw[2 * c])     : "v"(s1[4 * c]),     "v"(s1[4 * c + 1]));
                        asm("v_cvt_pk_bf16_f32 %0, %1, %2" : "=v"(pw[2 * c + 1]) : "v"(s1[4 * c + 2]), "v"(s1[4 * c + 3]));
                    }
                    asm("v_permlane32_swap_b32 %0, %1" : "+v"(pw[0]), "+v"(pw[2]));
                    asm("v_permlane32_swap_b32 %0, %1" : "+v"(pw[1]), "+v"(pw[3]));
                    asm("v_permlane32_swap_b32 %0, %1" : "+v"(pw[4]), "+v"(pw[6]));
                    asm("v_permlane32_swap_b32 %0, %1" : "+v"(pw[5]), "+v"(pw[7]));
                    uint4 g0 = {pw[0], pw[1], pw[2], pw[3]};
                    uint4 g1 = {pw[4], pw[5], pw[6], pw[7]};
                    pa[2] = __builtin_bit_cast(bf16x8_t, g0);
                    pa[3] = __builtin_bit_cast(bf16x8_t, g1);
                }
            }

            // ---- O += P @ V ----
            __builtin_amdgcn_s_setprio(1);
            const int ns = full ? 4 : 2;
#pragma unroll
            for (int s = 0; s < 4; ++s) {
                if (s >= ns) break;
                const int g = ((2 * s + hi) ^ (lid & 7)) << 3;
                bf16x8_t v0f = *reinterpret_cast<const bf16x8_t*>(&Vs[cur][lid][g]);
                bf16x8_t v1f = *reinterpret_cast<const bf16x8_t*>(&Vs[cur][lid + 32][g]);
                o0 = __builtin_amdgcn_mfma_f32_32x32x16_bf16(pa[s], v0f, o0, 0, 0, 0);
                o1 = __builtin_amdgcn_mfma_f32_32x32x16_bf16(pa[s], v1f, o1, 0, 0, 0);
            }
            __builtin_amdgcn_s_setprio(0);
        }

        // late write of prefetched tile, single barrier
        if (pre) {
            *reinterpret_cast<uint4*>(&Ks[nxt][ss][swz]) = kr0;
            *reinterpret_cast<uint4*>(&Ks[nxt][ss + 32][swz]) = kr1;
            *reinterpret_cast<uint4*>(&Vs[nxt][ss][swz]) = vr0;
            *reinterpret_cast<uint4*>(&Vs[nxt][ss + 32][swz]) = vr1;
            __syncthreads();
        }
    }

    // ---- epilogue: write partials. po[ck][bh][qt][q 0..127][d], l[ck][bh][qt][q] ----
    {
        u16* pob = po + (size_t)ck * 4194304;            // 4,194,304 u16 per chunk slot
        const int rowb = (hdix * 32 + qt) * 128;
#pragma unroll
        for (int r = 0; r < 16; ++r) {
            int qr = (r & 3) + 8 * (r >> 2) + 4 * hi;
            size_t base = (size_t)(rowb + wave * 32 + qr) * HD;
            pob[base + lid]      = f2bf(o0[r]);
            pob[base + lid + 32] = f2bf(o1[r]);
        }
        if (hi == 0)
            lb[(size_t)ck * 65536 + rowb + wave * 32 + lid] = l;
    }
}

// ---------------- launch ----------------
extern "C" void kernel_launch(void* const* d_in, const int* in_sizes, int n_in,
                              void* d_out, int out_size, void* d_ws, size_t ws_size,
                              hipStream_t stream)
{
    const float* x  = (const float*)d_in[0];
    const float* Wq = (const float*)d_in[1];
    const float* bq = (const float*)d_in[2];
    const float* Wk = (const float*)d_in[3];
    const float* bk = (const float*)d_in[4];
    const float* Wv = (const float*)d_in[5];
    const float* bv = (const float*)d_in[6];
    const float* Wo = (const float*)d_in[7];
    float* out = (float*)d_out;

    char* ws = (char*)d_ws;
    u16*   WqkvT = (u16*)(ws);                  // [768][512] bf16
    u16*   WoT   = (u16*)(ws + 786432);         // [512][512] bf16
    float* cost  = (float*)(ws + 1310720);      // [4096][32] f32
    float* sint  = (float*)(ws + 1835008);      // [4096][32] f32
    u16*   qw    = (u16*)(ws + 10747904);       // [2][8][4096][64] bf16 (scale*log2e folded)
    u16*   kw    = (u16*)(ws + 19136512);       // [2][2][4096][64] bf16
    u16*   vt    = (u16*)(ws + 21233664);       // [2][2][64][4096] bf16 (transposed V)
    u16*   po    = (u16*)(ws + 31719424);       // partial O [2][65536][64] bf16 (ends 48,496,640)
    float* lb    = (float*)(ws + 48496640);     // partial l [2][65536] f32 (ends 49,020,928)

    // ONE fused prep launch: 786,432 threads -> 3072 blocks (cvt segment gone: gemm<1> reads x f32)
    prep_kernel<<<3072, 256, 0, stream>>>(Wq, Wk, Wv, Wo, WqkvT, WoT, cost, sint);

    // QKV projection: A staged directly from fp32 x (ASRC=1)
    dim3 gp(64, 6);
    gemm_kernel<1, 1><<<gp, 256, 0, stream>>>(nullptr, x, nullptr, nullptr, WqkvT, 512,
                                              nullptr, 768,
                                              bq, bk, bv, cost, sint, qw, kw, vt);

    dim3 ga(2 * NH, 32, 2);   // x = bh (fastest -> XCD-local K/V), y: qt = 31-y, z = chunk
    attn_kernel<<<ga, 256, 0, stream>>>(qw, kw, vt, po, lb);

    // Out projection: A staged from split-KV partials with fused combine (ASRC=2)
    dim3 go(64, 4);
    gemm_kernel<0, 2><<<go, 256, 0, stream>>>(po, nullptr, po + 4194304, lb, WoT, 512,
                                              out, 512,
                                              nullptr, nullptr, nullptr, nullptr, nullptr,
                                              nullptr, nullptr, nullptr);
}

// Round 17
// 133.453 us; speedup vs baseline: 1.0266x; 1.0266x over previous
//
#include <hip/hip_runtime.h>

typedef unsigned short u16;
typedef unsigned int u32;
typedef __bf16 bf16x8_t __attribute__((ext_vector_type(8)));
typedef float f32x4_t __attribute__((ext_vector_type(4)));
typedef float f32x16_t __attribute__((ext_vector_type(16)));

#define T_SEQ 4096
#define EMB 512
#define NH 8
#define NKV 2
#define HD 64

__device__ __forceinline__ float bf2f(u16 h) {
    union { unsigned u; float f; } x; x.u = ((unsigned)h) << 16; return x.f;
}
__device__ __forceinline__ u16 f2bf(float f) {
    union { float f; unsigned u; } x; x.f = f;
    unsigned r = x.u + 0x7FFFu + ((x.u >> 16) & 1u);
    return (u16)(r >> 16);
}

// ------------- fused prep: weight transposes + RoPE tables, ONE launch -------------
// [0, 262144) WqT | [262144, 327680) WkT | [327680, 393216) WvT | [393216, 655360) WoT
// [655360, 786432) rope tables.  Total 786,432 threads = 3072 blocks.
__global__ __launch_bounds__(256)
void prep_kernel(const float* __restrict__ Wq, const float* __restrict__ Wk,
                 const float* __restrict__ Wv, const float* __restrict__ Wo,
                 u16* __restrict__ WqkvT, u16* __restrict__ WoT,
                 float* __restrict__ cost, float* __restrict__ sint)
{
    int i = blockIdx.x * 256 + threadIdx.x;
    if (i < 262144) {
        int n = i >> 9, k = i & 511;
        WqkvT[i] = f2bf(Wq[(size_t)k * 512 + n]);
    } else if (i < 327680) {
        int j = i - 262144;
        int n = j >> 9, k = j & 511;
        WqkvT[i] = f2bf(Wk[(size_t)k * 128 + n]);
    } else if (i < 393216) {
        int j = i - 327680;
        int n = j >> 9, k = j & 511;
        WqkvT[i] = f2bf(Wv[(size_t)k * 128 + n]);
    } else if (i < 655360) {
        int j = i - 393216;
        int n = j >> 9, k = j & 511;
        WoT[j] = f2bf(Wo[(size_t)k * 512 + n]);
    } else {
        int j = i - 655360;
        int t = j >> 5, jj = j & 31;
        double invf = pow(1.0e6, -(double)jj / 32.0);
        double ang = (double)t * invf;
        cost[j] = (float)cos(ang);
        sint[j] = (float)sin(ang);
    }
}

// ---------------- GEMM: C[M,N] = A[M,K](bf16) @ Bt[N,K](bf16)^T ----------------
// ASRC: 0 = A is bf16 (direct); 1 = A is fp32 (convert in staging).
// EPI:  0 = fp32 store to C; 1 = QKV epilogue (bias+RoPE+scatter q/k + transposed V).
template <int EPI, int ASRC>
__global__ __launch_bounds__(256)
void gemm_kernel(const u16* __restrict__ A, const float* __restrict__ Af32,
                 const u16* __restrict__ Bt, int K,
                 float* __restrict__ C, int N,
                 const float* __restrict__ bq, const float* __restrict__ bk,
                 const float* __restrict__ bv,
                 const float* __restrict__ cost, const float* __restrict__ sint,
                 u16* __restrict__ qw, u16* __restrict__ kw, u16* __restrict__ vt)
{
    __shared__ __align__(16) u16 As[128][72];
    __shared__ __align__(16) u16 Bs[128][72];

    const int tid  = threadIdx.x;
    const int lane = tid & 63, wave = tid >> 6;
    const int wr = wave >> 1, wc = wave & 1;
    const int tm = blockIdx.x, tn = blockIdx.y;
    const int lrow = lane & 15, lgrp = lane >> 4;

    f32x4_t acc[4][4];
#pragma unroll
    for (int i = 0; i < 4; ++i)
#pragma unroll
        for (int j = 0; j < 4; ++j) acc[i][j] = (f32x4_t){0.f, 0.f, 0.f, 0.f};

    for (int k0 = 0; k0 < K; k0 += 64) {
        __syncthreads();
        {
            const int r0 = tid >> 3;
            const int ko = (tid & 7) * 8;
#pragma unroll
            for (int rr = 0; rr < 4; ++rr) {
                int row = r0 + rr * 32;
                int grow = tm * 128 + row;
                if (ASRC == 0) {
                    uint4 va = *reinterpret_cast<const uint4*>(A + (size_t)grow * K + k0 + ko);
                    *reinterpret_cast<uint4*>(&As[row][ko]) = va;
                } else {
                    float4 f0 = *reinterpret_cast<const float4*>(Af32 + (size_t)grow * K + k0 + ko);
                    float4 f1 = *reinterpret_cast<const float4*>(Af32 + (size_t)grow * K + k0 + ko + 4);
                    u16 o[8] = { f2bf(f0.x), f2bf(f0.y), f2bf(f0.z), f2bf(f0.w),
                                 f2bf(f1.x), f2bf(f1.y), f2bf(f1.z), f2bf(f1.w) };
                    *reinterpret_cast<uint4*>(&As[row][ko]) = *reinterpret_cast<uint4*>(o);
                }
                uint4 vb = *reinterpret_cast<const uint4*>(Bt + (size_t)(tn * 128 + row) * K + k0 + ko);
                *reinterpret_cast<uint4*>(&Bs[row][ko]) = vb;
            }
        }
        __syncthreads();
#pragma unroll
        for (int kc = 0; kc < 2; ++kc) {
            bf16x8_t af[4], bf[4];
#pragma unroll
            for (int mb = 0; mb < 4; ++mb)
                af[mb] = *reinterpret_cast<const bf16x8_t*>(&As[wr * 64 + mb * 16 + lrow][kc * 32 + lgrp * 8]);
#pragma unroll
            for (int nb = 0; nb < 4; ++nb)
                bf[nb] = *reinterpret_cast<const bf16x8_t*>(&Bs[wc * 64 + nb * 16 + lrow][kc * 32 + lgrp * 8]);
#pragma unroll
            for (int mb = 0; mb < 4; ++mb)
#pragma unroll
                for (int nb = 0; nb < 4; ++nb)
                    acc[mb][nb] = __builtin_amdgcn_mfma_f32_16x16x32_bf16(af[mb], bf[nb], acc[mb][nb], 0, 0, 0);
        }
    }

    if (EPI == 0) {
#pragma unroll
        for (int mb = 0; mb < 4; ++mb)
#pragma unroll
            for (int nb = 0; nb < 4; ++nb)
#pragma unroll
                for (int r = 0; r < 4; ++r) {
                    int row = tm * 128 + wr * 64 + mb * 16 + lgrp * 4 + r;
                    int col = tn * 128 + wc * 64 + nb * 16 + lrow;
                    C[(size_t)row * N + col] = acc[mb][nb][r];
                }
    } else {
        const float QSC = 0.125f * 1.44269504088896f;   // head_dim^-0.5 * log2(e)
#pragma unroll
        for (int mb = 0; mb < 4; ++mb)
#pragma unroll
            for (int r = 0; r < 4; ++r) {
                int grow = tm * 128 + wr * 64 + mb * 16 + lgrp * 4 + r;
                int b = grow >> 12, t = grow & 4095;
#pragma unroll
                for (int nb = 0; nb < 2; ++nb) {
                    int n = tn * 128 + wc * 64 + nb * 16 + lrow;
                    int j = n & 63;
                    float c0 = acc[mb][nb][r];
                    float c1 = acc[mb][nb + 2][r];
                    if (n < 512) {               // Q (softmax runs in exp2 domain)
                        c0 += bq[n]; c1 += bq[n + 32];
                        float cs = cost[t * 32 + j], sn = sint[t * 32 + j];
                        float r0 = (c0 * cs - c1 * sn) * QSC;
                        float r1 = (c1 * cs + c0 * sn) * QSC;
                        int h = n >> 6;
                        size_t base = ((size_t)(b * NH + h) * T_SEQ + t) * HD;
                        qw[base + j]      = f2bf(r0);
                        qw[base + j + 32] = f2bf(r1);
                    } else if (n < 640) {        // K
                        int nn = n - 512;
                        c0 += bk[nn]; c1 += bk[nn + 32];
                        float cs = cost[t * 32 + j], sn = sint[t * 32 + j];
                        float r0 = c0 * cs - c1 * sn;
                        float r1 = c1 * cs + c0 * sn;
                        int hk2 = nn >> 6;
                        size_t base = ((size_t)(b * NKV + hk2) * T_SEQ + t) * HD;
                        kw[base + j]      = f2bf(r0);
                        kw[base + j + 32] = f2bf(r1);
                    } else {                     // V -> transposed vt[b][hk][d][t]
                        int nn = n - 640;
                        c0 += bv[nn]; c1 += bv[nn + 32];
                        int hv = nn >> 6;
                        size_t base = (size_t)(b * NKV + hv) * HD * T_SEQ;
                        vt[base + (size_t)j * T_SEQ + t]        = f2bf(c0);
                        vt[base + (size_t)(j + 32) * T_SEQ + t] = f2bf(c1);
                    }
                }
            }
    }
}

// ---------------- causal flash attention: split-KV (2 equal chunks), fixed-max softmax ----------------
// r12 config (best measured: 87us): grid (16 bh, 32 qt, 2 ck), x=bh fastest -> XCD-local K/V.
// qt = 31-y heavy-first; chunk ck covers [ck*(qt+1), (ck+1)*(qt+1)). 1024 blocks x 4 waves.
// permlane32_swap P-repack; hoisted-zero QK accumulator; fixed m=16 exp2-domain softmax.
__global__ __launch_bounds__(256)
void attn_kernel(const u16* __restrict__ qw, const u16* __restrict__ kw,
                 const u16* __restrict__ vt, u16* __restrict__ po, float* __restrict__ lb)
{
    __shared__ __align__(16) u16 Ks[2][64][64];   // [buf][kv][d], 16B-granule XOR swizzle
    __shared__ __align__(16) u16 Vs[2][64][64];   // [buf][d][kv], same swizzle

    const int hdix = blockIdx.x;                  // bh (fastest -> XCD L2 locality)
    const int b = hdix >> 3, h = hdix & 7, hk = h >> 2;
    const int qt = 31 - (int)blockIdx.y;          // heavy-first
    const int ck = blockIdx.z;                    // kv chunk
    const int tid = threadIdx.x, lane = tid & 63, wave = tid >> 6;
    const int lid = lane & 31, hi = lane >> 5;
    const int q0 = qt * 128 + wave * 32;
    const int kt0 = ck * (qt + 1);
    const int kt1 = kt0 + (qt + 1);

    const u16* kbase  = kw + (size_t)(b * NKV + hk) * T_SEQ * HD;
    const u16* vtbase = vt + (size_t)(b * NKV + hk) * HD * T_SEQ;

    const int ss = tid >> 3;                 // 0..31
    const int sg = tid & 7;                  // 16B granule
    const int swz = (sg ^ (ss & 7)) << 3;    // (ss+32)&7 == ss&7

    bf16x8_t qf[4];
    {
        const u16* qrow = qw + ((size_t)(b * NH + h) * T_SEQ + q0 + lid) * HD + 8 * hi;
#pragma unroll
        for (int t = 0; t < 4; ++t)
            qf[t] = *reinterpret_cast<const bf16x8_t*>(qrow + 16 * t);
    }

    f32x16_t o0, o1, z16;
#pragma unroll
    for (int i = 0; i < 16; ++i) { o0[i] = 0.f; o1[i] = 0.f; z16[i] = 0.f; }
    const float M_FIX = 16.0f;               // fixed softmax max (exp2 domain)
    float l = 0.f;

    // prologue: stage tile kt0 into buffer 0
    {
        const int s2 = kt0 * 64;
        uint4 ka  = *reinterpret_cast<const uint4*>(kbase + (size_t)(s2 + ss) * HD + sg * 8);
        uint4 kb2 = *reinterpret_cast<const uint4*>(kbase + (size_t)(s2 + ss + 32) * HD + sg * 8);
        uint4 va  = *reinterpret_cast<const uint4*>(vtbase + (size_t)ss * T_SEQ + s2 + sg * 8);
        uint4 vb2 = *reinterpret_cast<const uint4*>(vtbase + (size_t)(ss + 32) * T_SEQ + s2 + sg * 8);
        *reinterpret_cast<uint4*>(&Ks[0][ss][swz]) = ka;
        *reinterpret_cast<uint4*>(&Ks[0][ss + 32][swz]) = kb2;
        *reinterpret_cast<uint4*>(&Vs[0][ss][swz]) = va;
        *reinterpret_cast<uint4*>(&Vs[0][ss + 32][swz]) = vb2;
    }
    __syncthreads();

    for (int kt = kt0; kt < kt1; ++kt) {
        const int cur = (kt - kt0) & 1, nxt = cur ^ 1;
        const bool pre = (kt + 1 < kt1);

        uint4 kr0, kr1, vr0, vr1;
        if (pre) {
            const int s2 = (kt + 1) * 64;
            kr0 = *reinterpret_cast<const uint4*>(kbase + (size_t)(s2 + ss) * HD + sg * 8);
            kr1 = *reinterpret_cast<const uint4*>(kbase + (size_t)(s2 + ss + 32) * HD + sg * 8);
            vr0 = *reinterpret_cast<const uint4*>(vtbase + (size_t)ss * T_SEQ + s2 + sg * 8);
            vr1 = *reinterpret_cast<const uint4*>(vtbase + (size_t)(ss + 32) * T_SEQ + s2 + sg * 8);
        }

        if (kt * 64 <= q0 + 31) {            // wave has visible kv in this tile
            const bool full = (kt * 64 + 32 <= q0 + 31);   // s1 half (kv+32) visible?
            const bool mreq = (kt * 64 + 63 > q0);         // any masking needed?

            // ---- S^T = K_tile . Q^T  (t=0 uses hoisted zero C) ----
            f32x16_t s0, s1;
            __builtin_amdgcn_s_setprio(1);
#pragma unroll
            for (int t = 0; t < 4; ++t) {
                const int g = ((2 * t + hi) ^ (lid & 7)) << 3;
                bf16x8_t ka = *reinterpret_cast<const bf16x8_t*>(&Ks[cur][lid][g]);
                s0 = __builtin_amdgcn_mfma_f32_32x32x16_bf16(ka, qf[t], (t == 0) ? z16 : s0, 0, 0, 0);
                if (full) {
                    bf16x8_t kb2 = *reinterpret_cast<const bf16x8_t*>(&Ks[cur][lid + 32][g]);
                    s1 = __builtin_amdgcn_mfma_f32_32x32x16_bf16(kb2, qf[t], (t == 0) ? z16 : s1, 0, 0, 0);
                }
            }
            __builtin_amdgcn_s_setprio(0);

            // ---- causal mask ----
            if (mreq) {
                const int qg = q0 + lid;
                const int kvb = kt * 64 + 4 * hi;
#pragma unroll
                for (int r = 0; r < 16; ++r) {
                    int kv = kvb + (r & 3) + 8 * (r >> 2);
                    if (kv > qg) s0[r] = -1e30f;
                    if (full && kv + 32 > qg) s1[r] = -1e30f;
                }
            }

            // ---- softmax, exp2 domain, FIXED max ----
#pragma unroll
            for (int r = 0; r < 16; ++r) s0[r] = exp2f(s0[r] - M_FIX);
            if (full) {
#pragma unroll
                for (int r = 0; r < 16; ++r) s1[r] = exp2f(s1[r] - M_FIX);
            }

            {
                float rs = 0.f;
#pragma unroll
                for (int q4 = 0; q4 < 4; ++q4)
                    rs += (s0[4 * q4] + s0[4 * q4 + 1]) + (s0[4 * q4 + 2] + s0[4 * q4 + 3]);
                if (full) {
#pragma unroll
                    for (int q4 = 0; q4 < 4; ++q4)
                        rs += (s1[4 * q4] + s1[4 * q4 + 1]) + (s1[4 * q4 + 2] + s1[4 * q4 + 3]);
                }
                rs += __shfl_xor(rs, 32);
                l += rs;
            }

            // ---- in-register P repack -> PV A-fragments (cvt_pk + permlane32_swap) ----
            bf16x8_t pa[4];
            {
                u32 pw[8];
#pragma unroll
                for (int c = 0; c < 4; ++c) {
                    asm("v_cvt_pk_bf16_f32 %0, %1, %2" : "=v"(pw[2 * c])     : "v"(s0[4 * c]),     "v"(s0[4 * c + 1]));
                    asm("v_cvt_pk_bf16_f32 %0, %1, %2" : "=v"(pw[2 * c + 1]) : "v"(s0[4 * c + 2]), "v"(s0[4 * c + 3]));
                }
                asm("v_permlane32_swap_b32 %0, %1" : "+v"(pw[0]), "+v"(pw[2]));
                asm("v_permlane32_swap_b32 %0, %1" : "+v"(pw[1]), "+v"(pw[3]));
                asm("v_permlane32_swap_b32 %0, %1" : "+v"(pw[4]), "+v"(pw[6]));
                asm("v_permlane32_swap_b32 %0, %1" : "+v"(pw[5]), "+v"(pw[7]));
                uint4 f0 = {pw[0], pw[1], pw[2], pw[3]};
                uint4 f1 = {pw[4], pw[5], pw[6], pw[7]};
                pa[0] = __builtin_bit_cast(bf16x8_t, f0);
                pa[1] = __builtin_bit_cast(bf16x8_t, f1);
                if (full) {
#pragma unroll
                    for (int c = 0; c < 4; ++c) {
                        asm("v_cvt_pk_bf16_f32 %0, %1, %2" : "=v"(pw[2 * c])     : "v"(s1[4 * c]),     "v"(s1[4 * c + 1]));
                        asm("v_cvt_pk_bf16_f32 %0, %1, %2" : "=v"(pw[2 * c + 1]) : "v"(s1[4 * c + 2]), "v"(s1[4 * c + 3]));
                    }
                    asm("v_permlane32_swap_b32 %0, %1" : "+v"(pw[0]), "+v"(pw[2]));
                    asm("v_permlane32_swap_b32 %0, %1" : "+v"(pw[1]), "+v"(pw[3]));
                    asm("v_permlane32_swap_b32 %0, %1" : "+v"(pw[4]), "+v"(pw[6]));
                    asm("v_permlane32_swap_b32 %0, %1" : "+v"(pw[5]), "+v"(pw[7]));
                    uint4 g0 = {pw[0], pw[1], pw[2], pw[3]};
                    uint4 g1 = {pw[4], pw[5], pw[6], pw[7]};
                    pa[2] = __builtin_bit_cast(bf16x8_t, g0);
                    pa[3] = __builtin_bit_cast(bf16x8_t, g1);
                }
            }

            // ---- O += P @ V ----
            __builtin_amdgcn_s_setprio(1);
            const int ns = full ? 4 : 2;
#pragma unroll
            for (int s = 0; s < 4; ++s) {
                if (s >= ns) break;
                const int g = ((2 * s + hi) ^ (lid & 7)) << 3;
                bf16x8_t v0f = *reinterpret_cast<const bf16x8_t*>(&Vs[cur][lid][g]);
                bf16x8_t v1f = *reinterpret_cast<const bf16x8_t*>(&Vs[cur][lid + 32][g]);
                o0 = __builtin_amdgcn_mfma_f32_32x32x16_bf16(pa[s], v0f, o0, 0, 0, 0);
                o1 = __builtin_amdgcn_mfma_f32_32x32x16_bf16(pa[s], v1f, o1, 0, 0, 0);
            }
            __builtin_amdgcn_s_setprio(0);
        }

        // late write of prefetched tile, single barrier
        if (pre) {
            *reinterpret_cast<uint4*>(&Ks[nxt][ss][swz]) = kr0;
            *reinterpret_cast<uint4*>(&Ks[nxt][ss + 32][swz]) = kr1;
            *reinterpret_cast<uint4*>(&Vs[nxt][ss][swz]) = vr0;
            *reinterpret_cast<uint4*>(&Vs[nxt][ss + 32][swz]) = vr1;
            __syncthreads();
        }
    }

    // ---- epilogue: write partials. po[ck][bh][qt][q 0..127][d], l[ck][bh][qt][q] ----
    {
        u16* pob = po + (size_t)ck * 4194304;            // 4,194,304 u16 per chunk slot
        const int rowb = (hdix * 32 + qt) * 128;
#pragma unroll
        for (int r = 0; r < 16; ++r) {
            int qr = (r & 3) + 8 * (r >> 2) + 4 * hi;
            size_t base = (size_t)(rowb + wave * 32 + qr) * HD;
            pob[base + lid]      = f2bf(o0[r]);
            pob[base + lid + 32] = f2bf(o1[r]);
        }
        if (hi == 0)
            lb[(size_t)ck * 65536 + rowb + wave * 32 + lid] = l;
    }
}

// ---------------- combine: ao = (o0+o1)/(l0+l1), layout [B,T,H*D] bf16 ----------------
__global__ __launch_bounds__(256)
void combine_kernel(const u16* __restrict__ po, const float* __restrict__ lb,
                    u16* __restrict__ ao)
{
    int id = blockIdx.x * 256 + threadIdx.x;     // 65536 rows * 8 octets
    int row = id >> 3, oct = id & 7;
    int bhqt = row >> 7, qrow = row & 127;
    int bh = bhqt >> 5, qt = bhqt & 31;
    int b = bh >> 3, h = bh & 7;
    int t = qt * 128 + qrow;

    float inv = 1.0f / (lb[row] + lb[65536 + row]);
    const u16* p0 = po + (size_t)row * HD + oct * 8;
    const u16* p1 = p0 + 4194304;
    uint4 a = *reinterpret_cast<const uint4*>(p0);
    uint4 c = *reinterpret_cast<const uint4*>(p1);
    const u16* pa = reinterpret_cast<const u16*>(&a);
    const u16* pc = reinterpret_cast<const u16*>(&c);
    u16 outv[8];
#pragma unroll
    for (int j = 0; j < 8; ++j)
        outv[j] = f2bf((bf2f(pa[j]) + bf2f(pc[j])) * inv);
    size_t base = ((size_t)(b * T_SEQ) + t) * EMB + h * HD + oct * 8;
    *reinterpret_cast<uint2*>(ao + base)     = *reinterpret_cast<uint2*>(&outv[0]);
    *reinterpret_cast<uint2*>(ao + base + 4) = *reinterpret_cast<uint2*>(&outv[4]);
}

// ---------------- launch ----------------
extern "C" void kernel_launch(void* const* d_in, const int* in_sizes, int n_in,
                              void* d_out, int out_size, void* d_ws, size_t ws_size,
                              hipStream_t stream)
{
    const float* x  = (const float*)d_in[0];
    const float* Wq = (const float*)d_in[1];
    const float* bq = (const float*)d_in[2];
    const float* Wk = (const float*)d_in[3];
    const float* bk = (const float*)d_in[4];
    const float* Wv = (const float*)d_in[5];
    const float* bv = (const float*)d_in[6];
    const float* Wo = (const float*)d_in[7];
    float* out = (float*)d_out;

    char* ws = (char*)d_ws;
    u16*   WqkvT = (u16*)(ws);                  // [768][512] bf16
    u16*   WoT   = (u16*)(ws + 786432);         // [512][512] bf16
    float* cost  = (float*)(ws + 1310720);      // [4096][32] f32
    float* sint  = (float*)(ws + 1835008);      // [4096][32] f32
    u16*   qw    = (u16*)(ws + 10747904);       // [2][8][4096][64] bf16 (scale*log2e folded)
    u16*   kw    = (u16*)(ws + 19136512);       // [2][2][4096][64] bf16
    u16*   vt    = (u16*)(ws + 21233664);       // [2][2][64][4096] bf16 (transposed V)
    u16*   ao    = (u16*)(ws + 23330816);       // [8192][512] bf16 (ends 31,719,424)
    u16*   po    = (u16*)(ws + 31719424);       // partial O [2][65536][64] bf16 (ends 48,496,640)
    float* lb    = (float*)(ws + 48496640);     // partial l [2][65536] f32 (ends 49,020,928)

    // fused prep (no cvt segment; gemm<1> reads x fp32 directly)
    prep_kernel<<<3072, 256, 0, stream>>>(Wq, Wk, Wv, Wo, WqkvT, WoT, cost, sint);

    // QKV projection: A staged directly from fp32 x (ASRC=1)
    dim3 gp(64, 6);
    gemm_kernel<1, 1><<<gp, 256, 0, stream>>>(nullptr, x, WqkvT, 512,
                                              nullptr, 768,
                                              bq, bk, bv, cost, sint, qw, kw, vt);

    dim3 ga(2 * NH, 32, 2);   // x = bh (fastest -> XCD-local K/V), y: qt = 31-y, z = chunk
    attn_kernel<<<ga, 256, 0, stream>>>(qw, kw, vt, po, lb);

    combine_kernel<<<65536 * 8 / 256, 256, 0, stream>>>(po, lb, ao);

    // Out projection: plain bf16 A (ASRC=0)
    dim3 go(64, 4);
    gemm_kernel<0, 0><<<go, 256, 0, stream>>>(ao, nullptr, WoT, 512,
                                              out, 512,
                                              nullptr, nullptr, nullptr, nullptr, nullptr,
                                              nullptr, nullptr, nullptr);
}

// Round 18
// 129.976 us; speedup vs baseline: 1.0540x; 1.0268x over previous
//
#include <hip/hip_runtime.h>

typedef unsigned short u16;
typedef unsigned int u32;
typedef __bf16 bf16x8_t __attribute__((ext_vector_type(8)));
typedef float f32x4_t __attribute__((ext_vector_type(4)));
typedef float f32x16_t __attribute__((ext_vector_type(16)));

#define T_SEQ 4096
#define EMB 512
#define NH 8
#define NKV 2
#define HD 64

__device__ __forceinline__ float bf2f(u16 h) {
    union { unsigned u; float f; } x; x.u = ((unsigned)h) << 16; return x.f;
}
__device__ __forceinline__ u16 f2bf(float f) {
    union { float f; unsigned u; } x; x.f = f;
    unsigned r = x.u + 0x7FFFu + ((x.u >> 16) & 1u);
    return (u16)(r >> 16);
}

// ------------- fused prep: weight transposes + RoPE tables, ONE launch -------------
// [0, 262144) WqT | [262144, 327680) WkT | [327680, 393216) WvT | [393216, 655360) WoT
// [655360, 786432) rope tables.  Total 786,432 threads = 3072 blocks.
__global__ __launch_bounds__(256)
void prep_kernel(const float* __restrict__ Wq, const float* __restrict__ Wk,
                 const float* __restrict__ Wv, const float* __restrict__ Wo,
                 u16* __restrict__ WqkvT, u16* __restrict__ WoT,
                 float* __restrict__ cost, float* __restrict__ sint)
{
    int i = blockIdx.x * 256 + threadIdx.x;
    if (i < 262144) {
        int n = i >> 9, k = i & 511;
        WqkvT[i] = f2bf(Wq[(size_t)k * 512 + n]);
    } else if (i < 327680) {
        int j = i - 262144;
        int n = j >> 9, k = j & 511;
        WqkvT[i] = f2bf(Wk[(size_t)k * 128 + n]);
    } else if (i < 393216) {
        int j = i - 327680;
        int n = j >> 9, k = j & 511;
        WqkvT[i] = f2bf(Wv[(size_t)k * 128 + n]);
    } else if (i < 655360) {
        int j = i - 393216;
        int n = j >> 9, k = j & 511;
        WoT[j] = f2bf(Wo[(size_t)k * 512 + n]);
    } else {
        int j = i - 655360;
        int t = j >> 5, jj = j & 31;
        double invf = pow(1.0e6, -(double)jj / 32.0);
        double ang = (double)t * invf;
        cost[j] = (float)cos(ang);
        sint[j] = (float)sin(ang);
    }
}

// ---------------- GEMM: C[M,N] = A[M,K](bf16) @ Bt[N,K](bf16)^T, 64x128 tile ----------------
// 256 thr = 4 waves in 2x2; wave quadrant = 32 rows x 64 cols; acc[2][4].
// Balanced grids: QKV (128,6)=768 blocks = 3/CU; out (128,4)=512 = 2/CU.
// ASRC: 0 = A bf16; 1 = A fp32 (convert in staging).
// EPI:  0 = fp32 store; 1 = QKV epilogue (bias+RoPE+scatter q/k + transposed V).
template <int EPI, int ASRC>
__global__ __launch_bounds__(256)
void gemm_kernel(const u16* __restrict__ A, const float* __restrict__ Af32,
                 const u16* __restrict__ Bt, int K,
                 float* __restrict__ C, int N,
                 const float* __restrict__ bq, const float* __restrict__ bk,
                 const float* __restrict__ bv,
                 const float* __restrict__ cost, const float* __restrict__ sint,
                 u16* __restrict__ qw, u16* __restrict__ kw, u16* __restrict__ vt)
{
    __shared__ __align__(16) u16 As[64][72];
    __shared__ __align__(16) u16 Bs[128][72];

    const int tid  = threadIdx.x;
    const int lane = tid & 63, wave = tid >> 6;
    const int wr = wave >> 1, wc = wave & 1;    // 2x2 waves over 64x128
    const int tm = blockIdx.x, tn = blockIdx.y;
    const int lrow = lane & 15, lgrp = lane >> 4;

    f32x4_t acc[2][4];
#pragma unroll
    for (int i = 0; i < 2; ++i)
#pragma unroll
        for (int j = 0; j < 4; ++j) acc[i][j] = (f32x4_t){0.f, 0.f, 0.f, 0.f};

    for (int k0 = 0; k0 < K; k0 += 64) {
        __syncthreads();
        {
            const int r0 = tid >> 3;            // 0..31
            const int ko = (tid & 7) * 8;
            // A: 64 rows, 2 per thread
#pragma unroll
            for (int rr = 0; rr < 2; ++rr) {
                int row = r0 + rr * 32;
                int grow = tm * 64 + row;
                if (ASRC == 0) {
                    uint4 va = *reinterpret_cast<const uint4*>(A + (size_t)grow * K + k0 + ko);
                    *reinterpret_cast<uint4*>(&As[row][ko]) = va;
                } else {
                    float4 f0 = *reinterpret_cast<const float4*>(Af32 + (size_t)grow * K + k0 + ko);
                    float4 f1 = *reinterpret_cast<const float4*>(Af32 + (size_t)grow * K + k0 + ko + 4);
                    u16 o[8] = { f2bf(f0.x), f2bf(f0.y), f2bf(f0.z), f2bf(f0.w),
                                 f2bf(f1.x), f2bf(f1.y), f2bf(f1.z), f2bf(f1.w) };
                    *reinterpret_cast<uint4*>(&As[row][ko]) = *reinterpret_cast<uint4*>(o);
                }
            }
            // B: 128 rows, 4 per thread
#pragma unroll
            for (int rr = 0; rr < 4; ++rr) {
                int row = r0 + rr * 32;
                uint4 vb = *reinterpret_cast<const uint4*>(Bt + (size_t)(tn * 128 + row) * K + k0 + ko);
                *reinterpret_cast<uint4*>(&Bs[row][ko]) = vb;
            }
        }
        __syncthreads();
#pragma unroll
        for (int kc = 0; kc < 2; ++kc) {
            bf16x8_t af[2], bf[4];
#pragma unroll
            for (int mb = 0; mb < 2; ++mb)
                af[mb] = *reinterpret_cast<const bf16x8_t*>(&As[wr * 32 + mb * 16 + lrow][kc * 32 + lgrp * 8]);
#pragma unroll
            for (int nb = 0; nb < 4; ++nb)
                bf[nb] = *reinterpret_cast<const bf16x8_t*>(&Bs[wc * 64 + nb * 16 + lrow][kc * 32 + lgrp * 8]);
#pragma unroll
            for (int mb = 0; mb < 2; ++mb)
#pragma unroll
                for (int nb = 0; nb < 4; ++nb)
                    acc[mb][nb] = __builtin_amdgcn_mfma_f32_16x16x32_bf16(af[mb], bf[nb], acc[mb][nb], 0, 0, 0);
        }
    }

    if (EPI == 0) {
#pragma unroll
        for (int mb = 0; mb < 2; ++mb)
#pragma unroll
            for (int nb = 0; nb < 4; ++nb)
#pragma unroll
                for (int r = 0; r < 4; ++r) {
                    int row = tm * 64 + wr * 32 + mb * 16 + lgrp * 4 + r;
                    int col = tn * 128 + wc * 64 + nb * 16 + lrow;
                    C[(size_t)row * N + col] = acc[mb][nb][r];
                }
    } else {
        const float QSC = 0.125f * 1.44269504088896f;   // head_dim^-0.5 * log2(e)
#pragma unroll
        for (int mb = 0; mb < 2; ++mb)
#pragma unroll
            for (int r = 0; r < 4; ++r) {
                int grow = tm * 64 + wr * 32 + mb * 16 + lgrp * 4 + r;
                int b = grow >> 12, t = grow & 4095;
#pragma unroll
                for (int nb = 0; nb < 2; ++nb) {
                    int n = tn * 128 + wc * 64 + nb * 16 + lrow;   // low column of (d, d+32) pair
                    int j = n & 63;
                    float c0 = acc[mb][nb][r];
                    float c1 = acc[mb][nb + 2][r];
                    if (n < 512) {               // Q (softmax runs in exp2 domain)
                        c0 += bq[n]; c1 += bq[n + 32];
                        float cs = cost[t * 32 + j], sn = sint[t * 32 + j];
                        float r0 = (c0 * cs - c1 * sn) * QSC;
                        float r1 = (c1 * cs + c0 * sn) * QSC;
                        int h = n >> 6;
                        size_t base = ((size_t)(b * NH + h) * T_SEQ + t) * HD;
                        qw[base + j]      = f2bf(r0);
                        qw[base + j + 32] = f2bf(r1);
                    } else if (n < 640) {        // K
                        int nn = n - 512;
                        c0 += bk[nn]; c1 += bk[nn + 32];
                        float cs = cost[t * 32 + j], sn = sint[t * 32 + j];
                        float r0 = c0 * cs - c1 * sn;
                        float r1 = c1 * cs + c0 * sn;
                        int hk2 = nn >> 6;
                        size_t base = ((size_t)(b * NKV + hk2) * T_SEQ + t) * HD;
                        kw[base + j]      = f2bf(r0);
                        kw[base + j + 32] = f2bf(r1);
                    } else {                     // V -> transposed vt[b][hk][d][t]
                        int nn = n - 640;
                        c0 += bv[nn]; c1 += bv[nn + 32];
                        int hv = nn >> 6;
                        size_t base = (size_t)(b * NKV + hv) * HD * T_SEQ;
                        vt[base + (size_t)j * T_SEQ + t]        = f2bf(c0);
                        vt[base + (size_t)(j + 32) * T_SEQ + t] = f2bf(c1);
                    }
                }
            }
    }
}

// ---------------- causal flash attention: split-KV (2 equal chunks), fixed-max softmax ----------------
// r12 config (best measured: 87us): grid (16 bh, 32 qt, 2 ck), x=bh fastest -> XCD-local K/V.
// qt = 31-y heavy-first; chunk ck covers [ck*(qt+1), (ck+1)*(qt+1)). 1024 blocks x 4 waves.
// permlane32_swap P-repack; hoisted-zero QK accumulator; fixed m=16 exp2-domain softmax.
__global__ __launch_bounds__(256)
void attn_kernel(const u16* __restrict__ qw, const u16* __restrict__ kw,
                 const u16* __restrict__ vt, u16* __restrict__ po, float* __restrict__ lb)
{
    __shared__ __align__(16) u16 Ks[2][64][64];   // [buf][kv][d], 16B-granule XOR swizzle
    __shared__ __align__(16) u16 Vs[2][64][64];   // [buf][d][kv], same swizzle

    const int hdix = blockIdx.x;                  // bh (fastest -> XCD L2 locality)
    const int b = hdix >> 3, h = hdix & 7, hk = h >> 2;
    const int qt = 31 - (int)blockIdx.y;          // heavy-first
    const int ck = blockIdx.z;                    // kv chunk
    const int tid = threadIdx.x, lane = tid & 63, wave = tid >> 6;
    const int lid = lane & 31, hi = lane >> 5;
    const int q0 = qt * 128 + wave * 32;
    const int kt0 = ck * (qt + 1);
    const int kt1 = kt0 + (qt + 1);

    const u16* kbase  = kw + (size_t)(b * NKV + hk) * T_SEQ * HD;
    const u16* vtbase = vt + (size_t)(b * NKV + hk) * HD * T_SEQ;

    const int ss = tid >> 3;                 // 0..31
    const int sg = tid & 7;                  // 16B granule
    const int swz = (sg ^ (ss & 7)) << 3;    // (ss+32)&7 == ss&7

    bf16x8_t qf[4];
    {
        const u16* qrow = qw + ((size_t)(b * NH + h) * T_SEQ + q0 + lid) * HD + 8 * hi;
#pragma unroll
        for (int t = 0; t < 4; ++t)
            qf[t] = *reinterpret_cast<const bf16x8_t*>(qrow + 16 * t);
    }

    f32x16_t o0, o1, z16;
#pragma unroll
    for (int i = 0; i < 16; ++i) { o0[i] = 0.f; o1[i] = 0.f; z16[i] = 0.f; }
    const float M_FIX = 16.0f;               // fixed softmax max (exp2 domain)
    float l = 0.f;

    // prologue: stage tile kt0 into buffer 0
    {
        const int s2 = kt0 * 64;
        uint4 ka  = *reinterpret_cast<const uint4*>(kbase + (size_t)(s2 + ss) * HD + sg * 8);
        uint4 kb2 = *reinterpret_cast<const uint4*>(kbase + (size_t)(s2 + ss + 32) * HD + sg * 8);
        uint4 va  = *reinterpret_cast<const uint4*>(vtbase + (size_t)ss * T_SEQ + s2 + sg * 8);
        uint4 vb2 = *reinterpret_cast<const uint4*>(vtbase + (size_t)(ss + 32) * T_SEQ + s2 + sg * 8);
        *reinterpret_cast<uint4*>(&Ks[0][ss][swz]) = ka;
        *reinterpret_cast<uint4*>(&Ks[0][ss + 32][swz]) = kb2;
        *reinterpret_cast<uint4*>(&Vs[0][ss][swz]) = va;
        *reinterpret_cast<uint4*>(&Vs[0][ss + 32][swz]) = vb2;
    }
    __syncthreads();

    for (int kt = kt0; kt < kt1; ++kt) {
        const int cur = (kt - kt0) & 1, nxt = cur ^ 1;
        const bool pre = (kt + 1 < kt1);

        uint4 kr0, kr1, vr0, vr1;
        if (pre) {
            const int s2 = (kt + 1) * 64;
            kr0 = *reinterpret_cast<const uint4*>(kbase + (size_t)(s2 + ss) * HD + sg * 8);
            kr1 = *reinterpret_cast<const uint4*>(kbase + (size_t)(s2 + ss + 32) * HD + sg * 8);
            vr0 = *reinterpret_cast<const uint4*>(vtbase + (size_t)ss * T_SEQ + s2 + sg * 8);
            vr1 = *reinterpret_cast<const uint4*>(vtbase + (size_t)(ss + 32) * T_SEQ + s2 + sg * 8);
        }

        if (kt * 64 <= q0 + 31) {            // wave has visible kv in this tile
            const bool full = (kt * 64 + 32 <= q0 + 31);   // s1 half (kv+32) visible?
            const bool mreq = (kt * 64 + 63 > q0);         // any masking needed?

            // ---- S^T = K_tile . Q^T  (t=0 uses hoisted zero C) ----
            f32x16_t s0, s1;
            __builtin_amdgcn_s_setprio(1);
#pragma unroll
            for (int t = 0; t < 4; ++t) {
                const int g = ((2 * t + hi) ^ (lid & 7)) << 3;
                bf16x8_t ka = *reinterpret_cast<const bf16x8_t*>(&Ks[cur][lid][g]);
                s0 = __builtin_amdgcn_mfma_f32_32x32x16_bf16(ka, qf[t], (t == 0) ? z16 : s0, 0, 0, 0);
                if (full) {
                    bf16x8_t kb2 = *reinterpret_cast<const bf16x8_t*>(&Ks[cur][lid + 32][g]);
                    s1 = __builtin_amdgcn_mfma_f32_32x32x16_bf16(kb2, qf[t], (t == 0) ? z16 : s1, 0, 0, 0);
                }
            }
            __builtin_amdgcn_s_setprio(0);

            // ---- causal mask ----
            if (mreq) {
                const int qg = q0 + lid;
                const int kvb = kt * 64 + 4 * hi;
#pragma unroll
                for (int r = 0; r < 16; ++r) {
                    int kv = kvb + (r & 3) + 8 * (r >> 2);
                    if (kv > qg) s0[r] = -1e30f;
                    if (full && kv + 32 > qg) s1[r] = -1e30f;
                }
            }

            // ---- softmax, exp2 domain, FIXED max ----
#pragma unroll
            for (int r = 0; r < 16; ++r) s0[r] = exp2f(s0[r] - M_FIX);
            if (full) {
#pragma unroll
                for (int r = 0; r < 16; ++r) s1[r] = exp2f(s1[r] - M_FIX);
            }

            {
                float rs = 0.f;
#pragma unroll
                for (int q4 = 0; q4 < 4; ++q4)
                    rs += (s0[4 * q4] + s0[4 * q4 + 1]) + (s0[4 * q4 + 2] + s0[4 * q4 + 3]);
                if (full) {
#pragma unroll
                    for (int q4 = 0; q4 < 4; ++q4)
                        rs += (s1[4 * q4] + s1[4 * q4 + 1]) + (s1[4 * q4 + 2] + s1[4 * q4 + 3]);
                }
                rs += __shfl_xor(rs, 32);
                l += rs;
            }

            // ---- in-register P repack -> PV A-fragments (cvt_pk + permlane32_swap) ----
            bf16x8_t pa[4];
            {
                u32 pw[8];
#pragma unroll
                for (int c = 0; c < 4; ++c) {
                    asm("v_cvt_pk_bf16_f32 %0, %1, %2" : "=v"(pw[2 * c])     : "v"(s0[4 * c]),     "v"(s0[4 * c + 1]));
                    asm("v_cvt_pk_bf16_f32 %0, %1, %2" : "=v"(pw[2 * c + 1]) : "v"(s0[4 * c + 2]), "v"(s0[4 * c + 3]));
                }
                asm("v_permlane32_swap_b32 %0, %1" : "+v"(pw[0]), "+v"(pw[2]));
                asm("v_permlane32_swap_b32 %0, %1" : "+v"(pw[1]), "+v"(pw[3]));
                asm("v_permlane32_swap_b32 %0, %1" : "+v"(pw[4]), "+v"(pw[6]));
                asm("v_permlane32_swap_b32 %0, %1" : "+v"(pw[5]), "+v"(pw[7]));
                uint4 f0 = {pw[0], pw[1], pw[2], pw[3]};
                uint4 f1 = {pw[4], pw[5], pw[6], pw[7]};
                pa[0] = __builtin_bit_cast(bf16x8_t, f0);
                pa[1] = __builtin_bit_cast(bf16x8_t, f1);
                if (full) {
#pragma unroll
                    for (int c = 0; c < 4; ++c) {
                        asm("v_cvt_pk_bf16_f32 %0, %1, %2" : "=v"(pw[2 * c])     : "v"(s1[4 * c]),     "v"(s1[4 * c + 1]));
                        asm("v_cvt_pk_bf16_f32 %0, %1, %2" : "=v"(pw[2 * c + 1]) : "v"(s1[4 * c + 2]), "v"(s1[4 * c + 3]));
                    }
                    asm("v_permlane32_swap_b32 %0, %1" : "+v"(pw[0]), "+v"(pw[2]));
                    asm("v_permlane32_swap_b32 %0, %1" : "+v"(pw[1]), "+v"(pw[3]));
                    asm("v_permlane32_swap_b32 %0, %1" : "+v"(pw[4]), "+v"(pw[6]));
                    asm("v_permlane32_swap_b32 %0, %1" : "+v"(pw[5]), "+v"(pw[7]));
                    uint4 g0 = {pw[0], pw[1], pw[2], pw[3]};
                    uint4 g1 = {pw[4], pw[5], pw[6], pw[7]};
                    pa[2] = __builtin_bit_cast(bf16x8_t, g0);
                    pa[3] = __builtin_bit_cast(bf16x8_t, g1);
                }
            }

            // ---- O += P @ V ----
            __builtin_amdgcn_s_setprio(1);
            const int ns = full ? 4 : 2;
#pragma unroll
            for (int s = 0; s < 4; ++s) {
                if (s >= ns) break;
                const int g = ((2 * s + hi) ^ (lid & 7)) << 3;
                bf16x8_t v0f = *reinterpret_cast<const bf16x8_t*>(&Vs[cur][lid][g]);
                bf16x8_t v1f = *reinterpret_cast<const bf16x8_t*>(&Vs[cur][lid + 32][g]);
                o0 = __builtin_amdgcn_mfma_f32_32x32x16_bf16(pa[s], v0f, o0, 0, 0, 0);
                o1 = __builtin_amdgcn_mfma_f32_32x32x16_bf16(pa[s], v1f, o1, 0, 0, 0);
            }
            __builtin_amdgcn_s_setprio(0);
        }

        // late write of prefetched tile, single barrier
        if (pre) {
            *reinterpret_cast<uint4*>(&Ks[nxt][ss][swz]) = kr0;
            *reinterpret_cast<uint4*>(&Ks[nxt][ss + 32][swz]) = kr1;
            *reinterpret_cast<uint4*>(&Vs[nxt][ss][swz]) = vr0;
            *reinterpret_cast<uint4*>(&Vs[nxt][ss + 32][swz]) = vr1;
            __syncthreads();
        }
    }

    // ---- epilogue: write partials. po[ck][bh][qt][q 0..127][d], l[ck][bh][qt][q] ----
    {
        u16* pob = po + (size_t)ck * 4194304;            // 4,194,304 u16 per chunk slot
        const int rowb = (hdix * 32 + qt) * 128;
#pragma unroll
        for (int r = 0; r < 16; ++r) {
            int qr = (r & 3) + 8 * (r >> 2) + 4 * hi;
            size_t base = (size_t)(rowb + wave * 32 + qr) * HD;
            pob[base + lid]      = f2bf(o0[r]);
            pob[base + lid + 32] = f2bf(o1[r]);
        }
        if (hi == 0)
            lb[(size_t)ck * 65536 + rowb + wave * 32 + lid] = l;
    }
}

// ---------------- combine: ao = (o0+o1)/(l0+l1), layout [B,T,H*D] bf16 ----------------
__global__ __launch_bounds__(256)
void combine_kernel(const u16* __restrict__ po, const float* __restrict__ lb,
                    u16* __restrict__ ao)
{
    int id = blockIdx.x * 256 + threadIdx.x;     // 65536 rows * 8 octets
    int row = id >> 3, oct = id & 7;
    int bhqt = row >> 7, qrow = row & 127;
    int bh = bhqt >> 5, qt = bhqt & 31;
    int b = bh >> 3, h = bh & 7;
    int t = qt * 128 + qrow;

    float inv = 1.0f / (lb[row] + lb[65536 + row]);
    const u16* p0 = po + (size_t)row * HD + oct * 8;
    const u16* p1 = p0 + 4194304;
    uint4 a = *reinterpret_cast<const uint4*>(p0);
    uint4 c = *reinterpret_cast<const uint4*>(p1);
    const u16* pa = reinterpret_cast<const u16*>(&a);
    const u16* pc = reinterpret_cast<const u16*>(&c);
    u16 outv[8];
#pragma unroll
    for (int j = 0; j < 8; ++j)
        outv[j] = f2bf((bf2f(pa[j]) + bf2f(pc[j])) * inv);
    size_t base = ((size_t)(b * T_SEQ) + t) * EMB + h * HD + oct * 8;
    *reinterpret_cast<uint2*>(ao + base)     = *reinterpret_cast<uint2*>(&outv[0]);
    *reinterpret_cast<uint2*>(ao + base + 4) = *reinterpret_cast<uint2*>(&outv[4]);
}

// ---------------- launch ----------------
extern "C" void kernel_launch(void* const* d_in, const int* in_sizes, int n_in,
                              void* d_out, int out_size, void* d_ws, size_t ws_size,
                              hipStream_t stream)
{
    const float* x  = (const float*)d_in[0];
    const float* Wq = (const float*)d_in[1];
    const float* bq = (const float*)d_in[2];
    const float* Wk = (const float*)d_in[3];
    const float* bk = (const float*)d_in[4];
    const float* Wv = (const float*)d_in[5];
    const float* bv = (const float*)d_in[6];
    const float* Wo = (const float*)d_in[7];
    float* out = (float*)d_out;

    char* ws = (char*)d_ws;
    u16*   WqkvT = (u16*)(ws);                  // [768][512] bf16
    u16*   WoT   = (u16*)(ws + 786432);         // [512][512] bf16
    float* cost  = (float*)(ws + 1310720);      // [4096][32] f32
    float* sint  = (float*)(ws + 1835008);      // [4096][32] f32
    u16*   qw    = (u16*)(ws + 10747904);       // [2][8][4096][64] bf16 (scale*log2e folded)
    u16*   kw    = (u16*)(ws + 19136512);       // [2][2][4096][64] bf16
    u16*   vt    = (u16*)(ws + 21233664);       // [2][2][64][4096] bf16 (transposed V)
    u16*   ao    = (u16*)(ws + 23330816);       // [8192][512] bf16 (ends 31,719,424)
    u16*   po    = (u16*)(ws + 31719424);       // partial O [2][65536][64] bf16 (ends 48,496,640)
    float* lb    = (float*)(ws + 48496640);     // partial l [2][65536] f32 (ends 49,020,928)

    // fused prep (no cvt segment; gemm<1> reads x fp32 directly)
    prep_kernel<<<3072, 256, 0, stream>>>(Wq, Wk, Wv, Wo, WqkvT, WoT, cost, sint);

    // QKV projection: 64x128 tiles -> (128, 6) = 768 blocks = 3/CU balanced
    dim3 gp(128, 6);
    gemm_kernel<1, 1><<<gp, 256, 0, stream>>>(nullptr, x, WqkvT, 512,
                                              nullptr, 768,
                                              bq, bk, bv, cost, sint, qw, kw, vt);

    dim3 ga(2 * NH, 32, 2);   // x = bh (fastest -> XCD-local K/V), y: qt = 31-y, z = chunk
    attn_kernel<<<ga, 256, 0, stream>>>(qw, kw, vt, po, lb);

    combine_kernel<<<65536 * 8 / 256, 256, 0, stream>>>(po, lb, ao);

    // Out projection: 64x128 tiles -> (128, 4) = 512 blocks = 2/CU balanced
    dim3 go(128, 4);
    gemm_kernel<0, 0><<<go, 256, 0, stream>>>(ao, nullptr, WoT, 512,
                                              out, 512,
                                              nullptr, nullptr, nullptr, nullptr, nullptr,
                                              nullptr, nullptr, nullptr);
}